// Round 1
// baseline (273.328 us; speedup 1.0000x reference)
//
#include <hip/hip_runtime.h>
#include <math.h>

#define BB 32
#define SS 4096
#define DD 256
#define DAA 128
#define DPP 64
#define CHUNKS 32
#define ROWS_PER_BLOCK (SS / CHUNKS)                     // 128
#define WAVES_PER_BLOCK 4
#define ROWS_PER_WAVE (ROWS_PER_BLOCK / WAVES_PER_BLOCK) // 32

// workspace layout (float elements)
#define WS_VH   0
#define WS_VP1  256
#define WS_VP2  320
#define WS_QDOT 384
#define WS_PART 416
#define PART_STRIDE 258   // [m, l, ctx[256]]

// ---------------------------------------------------------------------------
// Kernel 0: fold Wc into projection vectors; compute per-batch q scalar.
// ---------------------------------------------------------------------------
__global__ void prep_kernel(const float* __restrict__ q,
                            const float* __restrict__ Wh,
                            const float* __restrict__ Wq,
                            const float* __restrict__ Wp1,
                            const float* __restrict__ Wp2,
                            const float* __restrict__ Wc,
                            const float* __restrict__ bc,
                            float* __restrict__ ws) {
    __shared__ float s_vq[DD];
    const int tid = threadIdx.x; // 256 threads
    float vh = 0.f, vq = 0.f;
    for (int a = 0; a < DAA; ++a) {
        vh += Wh[a * DD + tid] * Wc[a];
        vq += Wq[a * DD + tid] * Wc[DAA + a];
    }
    ws[WS_VH + tid] = vh;
    s_vq[tid] = vq;
    if (tid < DPP) {
        float vp1 = 0.f, vp2 = 0.f;
        for (int a = 0; a < DPP; ++a) {
            vp1 += Wp1[a * DPP + tid] * Wc[2 * DAA + a];
            vp2 += Wp2[a * DPP + tid] * Wc[2 * DAA + DPP + a];
        }
        ws[WS_VP1 + tid] = vp1;
        ws[WS_VP2 + tid] = vp2;
    }
    __syncthreads();
    if (tid < BB) {
        float acc = bc[0];
        for (int d = 0; d < DD; ++d) acc += q[tid * DD + d] * s_vq[d];
        ws[WS_QDOT + tid] = acc;
    }
}

// ---------------------------------------------------------------------------
// Kernel 1: single-pass online-softmax context over S-chunks.
// grid = (CHUNKS, B), block = 256 (4 waves). Each wave streams 32 rows.
// ---------------------------------------------------------------------------
__global__ __launch_bounds__(256) void
main_kernel(const float* __restrict__ h,
            const float* __restrict__ pf1,
            const float* __restrict__ pf2,
            float* __restrict__ ws) {
    const int c    = blockIdx.x;
    const int b    = blockIdx.y;
    const int tid  = threadIdx.x;
    const int wave = tid >> 6;
    const int lane = tid & 63;

    // per-lane constants: vh covers dims 4*lane..4*lane+3; vp covers dim=lane
    const float4 vh4  = ((const float4*)(ws + WS_VH))[lane];
    const float  vp1l = ws[WS_VP1 + lane];
    const float  vp2l = ws[WS_VP2 + lane];
    const float  qd   = ws[WS_QDOT + b];

    const int s0 = c * ROWS_PER_BLOCK;
    const float4* hbase  = (const float4*)(h + (size_t)b * SS * DD);
    const float*  p1base = pf1 + (size_t)b * SS * DPP;
    const float*  p2base = pf2 + (size_t)b * SS * DPP;

    float  m = -INFINITY, l = 0.f;
    float4 ctx = make_float4(0.f, 0.f, 0.f, 0.f);

    for (int i = 0; i < ROWS_PER_WAVE; ++i) {
        const int s = s0 + i * WAVES_PER_BLOCK + wave; // waves march together
        const float4 h4 = hbase[(size_t)s * (DD / 4) + lane];
        const float  p1 = p1base[s * DPP + lane];
        const float  p2 = p2base[s * DPP + lane];

        float part = h4.x * vh4.x + h4.y * vh4.y + h4.z * vh4.z + h4.w * vh4.w
                   + p1 * vp1l + p2 * vp2l;
        #pragma unroll
        for (int off = 32; off >= 1; off >>= 1)
            part += __shfl_xor(part, off, 64);

        const float score = part + qd;
        const float e2 = __expf(2.f * score);
        const float t  = (e2 - 1.f) / (e2 + 1.f);   // tanh(score)

        const float mn = fmaxf(m, t);
        const float sc = __expf(m - mn);            // 0 on first iter (m=-inf)
        const float w  = __expf(t - mn);
        l = l * sc + w;
        ctx.x = ctx.x * sc + w * h4.x;
        ctx.y = ctx.y * sc + w * h4.y;
        ctx.z = ctx.z * sc + w * h4.z;
        ctx.w = ctx.w * sc + w * h4.w;
        m = mn;
    }

    // combine the block's 4 waves
    __shared__ float s_m[WAVES_PER_BLOCK], s_l[WAVES_PER_BLOCK];
    __shared__ float s_ctx[WAVES_PER_BLOCK][DD];
    if (lane == 0) { s_m[wave] = m; s_l[wave] = l; }
    ((float4*)s_ctx[wave])[lane] = ctx;
    __syncthreads();

    const float M  = fmaxf(fmaxf(s_m[0], s_m[1]), fmaxf(s_m[2], s_m[3]));
    const float f0 = __expf(s_m[0] - M), f1 = __expf(s_m[1] - M);
    const float f2 = __expf(s_m[2] - M), f3 = __expf(s_m[3] - M);
    const float L  = f0 * s_l[0] + f1 * s_l[1] + f2 * s_l[2] + f3 * s_l[3];
    const float cd = f0 * s_ctx[0][tid] + f1 * s_ctx[1][tid]
                   + f2 * s_ctx[2][tid] + f3 * s_ctx[3][tid];

    float* part_out = ws + WS_PART + (size_t)(b * CHUNKS + c) * PART_STRIDE;
    if (tid == 0) { part_out[0] = M; part_out[1] = L; }
    part_out[2 + tid] = cd;
}

// ---------------------------------------------------------------------------
// Kernel 2: merge the CHUNKS partials per batch, scale by 1/(L*S).
// ---------------------------------------------------------------------------
__global__ void finalize_kernel(const float* __restrict__ ws,
                                float* __restrict__ out) {
    const int b   = blockIdx.x;
    const int tid = threadIdx.x; // 256
    __shared__ float s_m[CHUNKS], s_l[CHUNKS];
    const float* base = ws + WS_PART + (size_t)b * CHUNKS * PART_STRIDE;
    if (tid < CHUNKS) {
        s_m[tid] = base[(size_t)tid * PART_STRIDE + 0];
        s_l[tid] = base[(size_t)tid * PART_STRIDE + 1];
    }
    __syncthreads();
    float M = -INFINITY;
    #pragma unroll
    for (int c = 0; c < CHUNKS; ++c) M = fmaxf(M, s_m[c]);
    float L = 0.f, acc = 0.f;
    for (int c = 0; c < CHUNKS; ++c) {
        const float f = __expf(s_m[c] - M);
        L   += f * s_l[c];
        acc += f * base[(size_t)c * PART_STRIDE + 2 + tid];
    }
    out[b * DD + tid] = acc / (L * (float)SS);
}

extern "C" void kernel_launch(void* const* d_in, const int* in_sizes, int n_in,
                              void* d_out, int out_size, void* d_ws, size_t ws_size,
                              hipStream_t stream) {
    const float* h   = (const float*)d_in[0];
    const float* q   = (const float*)d_in[1];
    const float* pf1 = (const float*)d_in[2];
    const float* pf2 = (const float*)d_in[3];
    const float* Wh  = (const float*)d_in[4];
    const float* Wq  = (const float*)d_in[5];
    const float* Wp1 = (const float*)d_in[6];
    const float* Wp2 = (const float*)d_in[7];
    const float* Wc  = (const float*)d_in[8];
    const float* bc  = (const float*)d_in[9];
    float* out = (float*)d_out;
    float* ws  = (float*)d_ws;

    prep_kernel<<<1, 256, 0, stream>>>(q, Wh, Wq, Wp1, Wp2, Wc, bc, ws);
    main_kernel<<<dim3(CHUNKS, BB), 256, 0, stream>>>(h, pf1, pf2, ws);
    finalize_kernel<<<BB, 256, 0, stream>>>(ws, out);
}